// Round 1
// baseline (64.876 us; speedup 1.0000x reference)
//
#include <hip/hip_runtime.h>

// RSA layer, last-row-only, FUSED single-kernel u-split formulation.
//
// out[u] = (sum_j fs[j,u] * e^{s[j,u]}) / (sum_j e^{s[j,u]})
//   s[j,u] = sum_k fs[j,k] * v[k,u],   v[k,u] = w_hi[k,u] + w_dot[u]*input[k]
// (proj_hj[1023,:] and b are constant in j -> cancel in the softmax over j;
//  |s| <~ 8 so e^s is fp32-safe without max subtraction.)
// fs[j,k] = state[k, j+1] for j<1023;  fs[1023,k] = input[k].
//
// Partitioning: 128 blocks = one output u each; NO cross-block combine ->
// no workspace, no second kernel, no atomics, deterministic. Each block
// streams the full state (512 KB) coalesced: thread t owns shifted columns
// j' = 4t..4t+3 (j = j'-1), reading state[k][4t..4t+3] as one aligned
// float4 per k with an 8-deep rolling register prefetch. Thread 0's dead
// j'=0 slot is patched to j=1023 (fs = input) via one cndmask per k.
// kdat[k] = {v[k,u], input[k]} lives in LDS; per unrolled iteration the
// read is a compile-time-constant-address ds_read_b64 (uniform broadcast).

constexpr int U = 128;
constexpr int W = 1024;

__global__ __launch_bounds__(256) void rsa_fused(
    const float* __restrict__ input,   // (128,)
    const float* __restrict__ state,   // (128,1024) row-major
    const float* __restrict__ w,       // (257,128) row-major
    float* __restrict__ out)           // (128,)
{
    const int u = blockIdx.x;          // 0..127: this block's output unit
    const int t = threadIdx.x;         // 0..255: shifted cols j' = 4t..4t+3

    __shared__ __align__(8) float kdat[U][2];  // {v[k][u], input[k]}
    __shared__ float red[4][2];                // per-wave {num, den}

    // ---- issue ALL global loads up front (one cold-latency round) ----
    const float* sp = state + 4 * t;   // column group base
    constexpr int PF = 8;              // rolling prefetch depth
    float4 pf[PF];
    #pragma unroll
    for (int i = 0; i < PF; ++i)
        pf[i] = *(const float4*)(sp + i * W);

    // numerator weights: fs[j,u] = state[u, j'] = state[u][4t+i]
    float4 nw = *(const float4*)(state + (size_t)u * W + 4 * t);
    const float in_u = input[u];       // uniform broadcast load

    float vk = 0.f, ik = 0.f;
    if (t < U) {
        const float whi = w[t * U + u];          // w_hi[k=t, u] (strided)
        ik = input[t];
        const float wd = w[2 * U * U + u];       // w_dot[u] (uniform)
        vk = fmaf(wd, ik, whi);                  // v[k,u]
    }

    if (t < U) { kdat[t][0] = vk; kdat[t][1] = ik; }
    __syncthreads();                             // kdat ready

    // ---- s[j', u] accumulation over k (GEMV per thread, 4 j's) ----
    const bool t0 = (t == 0);
    float4 acc = {0.f, 0.f, 0.f, 0.f};
    #pragma unroll
    for (int k = 0; k < U; ++k) {
        float4 cur = pf[k & (PF - 1)];
        if (k + PF < U)
            pf[k & (PF - 1)] = *(const float4*)(sp + (k + PF) * W);
        const float2 kd = *(const float2*)&kdat[k][0];   // {v_k, input_k}
        const float fs0 = t0 ? kd.y : cur.x;             // patch j'=0 -> j=1023
        acc.x = fmaf(fs0,   kd.x, acc.x);
        acc.y = fmaf(cur.y, kd.x, acc.y);
        acc.z = fmaf(cur.z, kd.x, acc.z);
        acc.w = fmaf(cur.w, kd.x, acc.w);
    }

    // ---- softmax partials (no max-sub; |s| small) ----
    if (t0) nw.x = in_u;                // weight for patched slot: fs[1023,u]
    float4 e;
    e.x = __expf(acc.x); e.y = __expf(acc.y);
    e.z = __expf(acc.z); e.w = __expf(acc.w);
    float num = nw.x * e.x + nw.y * e.y + nw.z * e.z + nw.w * e.w;
    float den = e.x + e.y + e.z + e.w;

    // ---- block reduce: wave shfl tree, then 4-wave merge ----
    #pragma unroll
    for (int o = 32; o >= 1; o >>= 1) {
        num += __shfl_down(num, o, 64);
        den += __shfl_down(den, o, 64);
    }
    const int lane = t & 63, wv = t >> 6;
    if (lane == 0) { red[wv][0] = num; red[wv][1] = den; }
    __syncthreads();
    if (t0) {
        const float n = red[0][0] + red[1][0] + red[2][0] + red[3][0];
        const float d = red[0][1] + red[1][1] + red[2][1] + red[3][1];
        out[u] = n / d;
    }
}

extern "C" void kernel_launch(void* const* d_in, const int* in_sizes, int n_in,
                              void* d_out, int out_size, void* d_ws, size_t ws_size,
                              hipStream_t stream) {
    const float* input = (const float*)d_in[0];   // (1,128)
    const float* state = (const float*)d_in[1];   // (128,1024)
    const float* w     = (const float*)d_in[2];   // (257,128)
    // d_in[3] = b (zeros; cancels in softmax) -- unused
    float* out = (float*)d_out;                   // (1,128)
    // d_ws unused: no cross-block combine needed.

    rsa_fused<<<dim3(128), dim3(256), 0, stream>>>(input, state, w, out);
}